// Round 1
// baseline (232.908 us; speedup 1.0000x reference)
//
#include <hip/hip_runtime.h>
#include <hip/hip_bf16.h>

// RhymeLoss: mean over b in [0,4096), pairs i<j in [0,32) of
//   same(i,j) ? 1 - cos(u_i,u_j) : relu(cos(u_i,u_j) - 0.5)
// Strategy: one wave per batch. Gram G = U U^T via mfma_f32_16x16x32_bf16,
// fragments loaded straight from global (A-frag == B-frag for a gram), norms
// from the gram diagonal, loss in the epilogue, atomicAdd of scaled partials.

typedef short bf16x8 __attribute__((ext_vector_type(8)));   // 8 bf16 in 4 VGPRs
typedef float f32x4  __attribute__((ext_vector_type(4)));

#define MARGIN 0.5f
#define EPS_NORM 1e-8f
#define NPAIR_INV (1.0f / 2031616.0f)   // 1 / (4096 * 496)

// fp32 -> bf16 round-to-nearest-even (inputs are finite, no NaN handling)
static __device__ __forceinline__ short f2bf(float f) {
    unsigned u = __float_as_uint(f);
    u += 0x7fffu + ((u >> 16) & 1u);
    return (short)(u >> 16);
}

__global__ __launch_bounds__(256) void rhyme_loss_kernel(
    const float* __restrict__ emb,   // [4096][32][256] fp32
    const int*   __restrict__ sch,   // [4096][32] int32
    float*       __restrict__ out)   // [1] fp32 (pre-zeroed)
{
    __shared__ float s_diag[4][32];
    __shared__ float s_inv[4][32];
    __shared__ int   s_sch[4][32];

    const int tid  = threadIdx.x;
    const int w    = tid >> 6;            // wave id within block, 0..3
    const int lane = tid & 63;
    const int b    = blockIdx.x * 4 + w;  // batch index, one wave per batch

    const int q = lane >> 4;              // quad 0..3 -> k-offset q*8
    const int c = lane & 15;              // fragment row (= C col)

    // Lane's global source: row c (frag0) / row 16+c (frag1), cols kc+q*8..+7
    const float* base0 = emb + (size_t)b * 8192 + (size_t)c * 256 + q * 8;
    const float* base1 = base0 + 16 * 256;

    f32x4 acc00 = {0.f, 0.f, 0.f, 0.f};   // rows 0-15  x cols 0-15
    f32x4 acc01 = {0.f, 0.f, 0.f, 0.f};   // rows 0-15  x cols 16-31
    f32x4 acc11 = {0.f, 0.f, 0.f, 0.f};   // rows 16-31 x cols 16-31
    // (tile 10 is the i>j mirror of 01 -> never needed)

    #pragma unroll
    for (int kc = 0; kc < 256; kc += 32) {
        const float4* p0 = (const float4*)(base0 + kc);
        const float4* p1 = (const float4*)(base1 + kc);
        float4 a0 = p0[0], a1 = p0[1];
        float4 b0 = p1[0], b1 = p1[1];

        bf16x8 f0, f1;
        f0[0] = f2bf(a0.x); f0[1] = f2bf(a0.y); f0[2] = f2bf(a0.z); f0[3] = f2bf(a0.w);
        f0[4] = f2bf(a1.x); f0[5] = f2bf(a1.y); f0[6] = f2bf(a1.z); f0[7] = f2bf(a1.w);
        f1[0] = f2bf(b0.x); f1[1] = f2bf(b0.y); f1[2] = f2bf(b0.z); f1[3] = f2bf(b0.w);
        f1[4] = f2bf(b1.x); f1[5] = f2bf(b1.y); f1[6] = f2bf(b1.z); f1[7] = f2bf(b1.w);

        // A-frag and B-frag of a gram share the same per-lane data.
        acc00 = __builtin_amdgcn_mfma_f32_16x16x32_bf16(f0, f0, acc00, 0, 0, 0);
        acc01 = __builtin_amdgcn_mfma_f32_16x16x32_bf16(f0, f1, acc01, 0, 0, 0);
        acc11 = __builtin_amdgcn_mfma_f32_16x16x32_bf16(f1, f1, acc11, 0, 0, 0);
    }

    // C/D layout (m89-verified): col = lane&15, row = (lane>>4)*4 + reg.
    // Diagonal of tiles 00/11: row==col -> reg = c - 4*q when in [0,4).
    const int dreg = c - 4 * q;
    if (dreg >= 0 && dreg < 4) {
        s_diag[w][c]      = acc00[dreg];   // ||u_c||^2
        s_diag[w][16 + c] = acc11[dreg];   // ||u_{16+c}||^2
    }
    __syncthreads();

    if (lane < 32) {
        float d = s_diag[w][lane];
        s_inv[w][lane] = 1.0f / fmaxf(sqrtf(d), EPS_NORM);
        s_sch[w][lane] = sch[b * 32 + lane];
    }
    __syncthreads();

    const float invj0 = s_inv[w][c];
    const float invj1 = s_inv[w][16 + c];
    const int   sj0   = s_sch[w][c];
    const int   sj1   = s_sch[w][16 + c];

    float sum = 0.0f;
    #pragma unroll
    for (int r = 0; r < 4; ++r) {
        const int   i0    = q * 4 + r;
        const float inv_i = s_inv[w][i0];
        const int   si    = s_sch[w][i0];

        // tile 01: i = i0 (<16), j = 16+c  -> always i<j
        {
            float sim = acc01[r] * inv_i * invj1;
            sum += (si == sj1) ? (1.0f - sim) : fmaxf(sim - MARGIN, 0.0f);
        }
        if (i0 < c) {
            // tile 00: i = i0, j = c
            float sim = acc00[r] * inv_i * invj0;
            sum += (si == sj0) ? (1.0f - sim) : fmaxf(sim - MARGIN, 0.0f);
            // tile 11: i = 16+i0, j = 16+c
            float sim2 = acc11[r] * s_inv[w][16 + i0] * invj1;
            sum += (s_sch[w][16 + i0] == sj1) ? (1.0f - sim2)
                                              : fmaxf(sim2 - MARGIN, 0.0f);
        }
    }

    // wave-64 reduction
    #pragma unroll
    for (int off = 32; off > 0; off >>= 1)
        sum += __shfl_down(sum, off, 64);

    if (lane == 0)
        atomicAdd(out, sum * NPAIR_INV);
}

extern "C" void kernel_launch(void* const* d_in, const int* in_sizes, int n_in,
                              void* d_out, int out_size, void* d_ws, size_t ws_size,
                              hipStream_t stream) {
    const float* emb = (const float*)d_in[0];
    const int*   sch = (const int*)d_in[1];
    float*       out = (float*)d_out;

    hipMemsetAsync(out, 0, sizeof(float), stream);   // d_out is poisoned 0xAA
    rhyme_loss_kernel<<<dim3(4096 / 4), dim3(256), 0, stream>>>(emb, sch, out);
}

// Round 2
// 220.250 us; speedup vs baseline: 1.0575x; 1.0575x over previous
//
#include <hip/hip_runtime.h>
#include <hip/hip_bf16.h>

// RhymeLoss: mean over b in [0,4096), pairs i<j in [0,32) of
//   same(i,j) ? 1 - cos(u_i,u_j) : relu(cos(u_i,u_j) - 0.5)
// One wave per batch. Gram G = U U^T via mfma_f32_16x16x32_bf16, fragments
// loaded straight from global (A-frag == B-frag for a gram), norms from the
// gram diagonal, loss epilogue, atomicAdd of scaled partials.
//
// R2 change: preload ALL 32 float4 per lane (the wave's whole 32 KiB batch)
// before any convert/MFMA, so all 32 global_load_dwordx4 are in flight
// simultaneously. R1 (interleaved load/convert) had ~1 load in flight and was
// latency-bound at 9% of HBM BW (VGPR=40, VALUBusy 3%).

typedef short bf16x8 __attribute__((ext_vector_type(8)));   // 8 bf16 in 4 VGPRs
typedef float f32x4  __attribute__((ext_vector_type(4)));

#define MARGIN 0.5f
#define EPS_NORM 1e-8f
#define NPAIR_INV (1.0f / 2031616.0f)   // 1 / (4096 * 496)

// fp32 -> bf16 round-to-nearest-even (inputs are finite, no NaN handling)
static __device__ __forceinline__ short f2bf(float f) {
    unsigned u = __float_as_uint(f);
    u += 0x7fffu + ((u >> 16) & 1u);
    return (short)(u >> 16);
}

__global__ __launch_bounds__(256) void rhyme_loss_kernel(
    const float* __restrict__ emb,   // [4096][32][256] fp32
    const int*   __restrict__ sch,   // [4096][32] int32
    float*       __restrict__ out)   // [1] fp32 (pre-zeroed)
{
    __shared__ float s_diag[4][32];
    __shared__ float s_inv[4][32];
    __shared__ int   s_sch[4][32];

    const int tid  = threadIdx.x;
    const int w    = tid >> 6;            // wave id within block, 0..3
    const int lane = tid & 63;
    const int b    = blockIdx.x * 4 + w;  // batch index, one wave per batch

    const int q = lane >> 4;              // quad 0..3 -> k-offset q*8
    const int c = lane & 15;              // fragment row (= C col)

    // Lane's global source: row c (frag0) / row 16+c (frag1), cols kc+q*8..+7
    const float* base0 = emb + (size_t)b * 8192 + (size_t)c * 256 + q * 8;
    const float* base1 = base0 + 16 * 256;

    // ---- Phase 1: issue every load up front (32 x dwordx4 in flight) ----
    float4 ra[16];   // frag0 data: chunk kc8 -> ra[2*kc8], ra[2*kc8+1]
    float4 rb[16];   // frag1 data
    #pragma unroll
    for (int kc8 = 0; kc8 < 8; ++kc8) {
        const float4* p0 = (const float4*)(base0 + kc8 * 32);
        const float4* p1 = (const float4*)(base1 + kc8 * 32);
        ra[2 * kc8]     = p0[0];
        ra[2 * kc8 + 1] = p0[1];
        rb[2 * kc8]     = p1[0];
        rb[2 * kc8 + 1] = p1[1];
    }

    f32x4 acc00 = {0.f, 0.f, 0.f, 0.f};   // rows 0-15  x cols 0-15
    f32x4 acc01 = {0.f, 0.f, 0.f, 0.f};   // rows 0-15  x cols 16-31
    f32x4 acc11 = {0.f, 0.f, 0.f, 0.f};   // rows 16-31 x cols 16-31
    // (tile 10 is the i>j mirror of 01 -> never needed)

    // ---- Phase 2: convert + MFMA ----
    #pragma unroll
    for (int kc8 = 0; kc8 < 8; ++kc8) {
        float4 a0 = ra[2 * kc8], a1 = ra[2 * kc8 + 1];
        float4 b0 = rb[2 * kc8], b1 = rb[2 * kc8 + 1];

        bf16x8 f0, f1;
        f0[0] = f2bf(a0.x); f0[1] = f2bf(a0.y); f0[2] = f2bf(a0.z); f0[3] = f2bf(a0.w);
        f0[4] = f2bf(a1.x); f0[5] = f2bf(a1.y); f0[6] = f2bf(a1.z); f0[7] = f2bf(a1.w);
        f1[0] = f2bf(b0.x); f1[1] = f2bf(b0.y); f1[2] = f2bf(b0.z); f1[3] = f2bf(b0.w);
        f1[4] = f2bf(b1.x); f1[5] = f2bf(b1.y); f1[6] = f2bf(b1.z); f1[7] = f2bf(b1.w);

        // A-frag and B-frag of a gram share the same per-lane data.
        acc00 = __builtin_amdgcn_mfma_f32_16x16x32_bf16(f0, f0, acc00, 0, 0, 0);
        acc01 = __builtin_amdgcn_mfma_f32_16x16x32_bf16(f0, f1, acc01, 0, 0, 0);
        acc11 = __builtin_amdgcn_mfma_f32_16x16x32_bf16(f1, f1, acc11, 0, 0, 0);
    }

    // C/D layout (m89-verified): col = lane&15, row = (lane>>4)*4 + reg.
    // Diagonal of tiles 00/11: row==col -> reg = c - 4*q when in [0,4).
    const int dreg = c - 4 * q;
    if (dreg >= 0 && dreg < 4) {
        s_diag[w][c]      = acc00[dreg];   // ||u_c||^2
        s_diag[w][16 + c] = acc11[dreg];   // ||u_{16+c}||^2
    }
    __syncthreads();

    if (lane < 32) {
        float d = s_diag[w][lane];
        s_inv[w][lane] = 1.0f / fmaxf(sqrtf(d), EPS_NORM);
        s_sch[w][lane] = sch[b * 32 + lane];
    }
    __syncthreads();

    const float invj0 = s_inv[w][c];
    const float invj1 = s_inv[w][16 + c];
    const int   sj0   = s_sch[w][c];
    const int   sj1   = s_sch[w][16 + c];

    float sum = 0.0f;
    #pragma unroll
    for (int r = 0; r < 4; ++r) {
        const int   i0    = q * 4 + r;
        const float inv_i = s_inv[w][i0];
        const int   si    = s_sch[w][i0];

        // tile 01: i = i0 (<16), j = 16+c  -> always i<j
        {
            float sim = acc01[r] * inv_i * invj1;
            sum += (si == sj1) ? (1.0f - sim) : fmaxf(sim - MARGIN, 0.0f);
        }
        if (i0 < c) {
            // tile 00: i = i0, j = c
            float sim = acc00[r] * inv_i * invj0;
            sum += (si == sj0) ? (1.0f - sim) : fmaxf(sim - MARGIN, 0.0f);
            // tile 11: i = 16+i0, j = 16+c
            float sim2 = acc11[r] * s_inv[w][16 + i0] * invj1;
            sum += (s_sch[w][16 + i0] == sj1) ? (1.0f - sim2)
                                              : fmaxf(sim2 - MARGIN, 0.0f);
        }
    }

    // wave-64 reduction
    #pragma unroll
    for (int off = 32; off > 0; off >>= 1)
        sum += __shfl_down(sum, off, 64);

    if (lane == 0)
        atomicAdd(out, sum * NPAIR_INV);
}

extern "C" void kernel_launch(void* const* d_in, const int* in_sizes, int n_in,
                              void* d_out, int out_size, void* d_ws, size_t ws_size,
                              hipStream_t stream) {
    const float* emb = (const float*)d_in[0];
    const int*   sch = (const int*)d_in[1];
    float*       out = (float*)d_out;

    hipMemsetAsync(out, 0, sizeof(float), stream);   // d_out is poisoned 0xAA
    rhyme_loss_kernel<<<dim3(4096 / 4), dim3(256), 0, stream>>>(emb, sch, out);
}